// Round 7
// baseline (543.836 us; speedup 1.0000x reference)
//
#include <hip/hip_runtime.h>
#include <hip/hip_cooperative_groups.h>

namespace cg = cooperative_groups;

#define HDIM 256
#define GB   768            // grid blocks (3/CU on 256 CUs -- co-residency safe)
#define BT   256            // threads per block
#define NREP 8              // histogram replicas (reduce per-address atomic contention)
#define NTH  (GB * BT)

// ONE cooperative kernel: zero -> count -> colsum -> reduce -> matvec -> rowdot -> gather.
// Rationale: rounds 2/3/5 showed a ~66us floor insensitive to per-kernel micro-opts;
// budget says work is ~25-35us => ~5-7us per graph node of serial launch overhead.
// grid.sync() replaces the 5 inter-kernel boundaries.
__global__ __launch_bounds__(BT, 4)
void k_fused(const float4* __restrict__ xs4,   // x_src  [Ns][64] float4
             const float4* __restrict__ xt4,   // x_trg  [Nt][64] float4
             const float*  __restrict__ Rm,    // R      [256][256]
             const int*    __restrict__ edge,  // [2E]: [0,E)=src, [E,2E)=trg
             int Ns, int Nt, int E,
             unsigned int* __restrict__ cnt,   // ws: [NREP*Ns]
             float* __restrict__ pT,           // ws: [HDIM][GB] transposed partials
             float* __restrict__ ls,           // ws: [HDIM]
             float* __restrict__ vv,           // ws: [HDIM]
             float* __restrict__ t,            // ws: [Nt]
             float* __restrict__ out)          // [E]
{
    cg::grid_group grid = cg::this_grid();
    const int tid = threadIdx.x;
    const int bid = blockIdx.x;
    const int g   = bid * BT + tid;

    __shared__ float sred[4 * HDIM];   // 4KB, reused across phases

    // ---------------- P0: zero the histogram replicas ----------------
    {
        const int tot = NREP * Ns;
        uint4* p4 = (uint4*)cnt;
        const int n4 = tot >> 2;
        for (int i = g; i < n4; i += NTH) p4[i] = make_uint4(0u, 0u, 0u, 0u);
        if (g < (tot & 3)) cnt[(n4 << 2) + g] = 0u;
    }
    grid.sync();

    // ---------------- P1: histogram of src indices (int atomics, deterministic) ----
    {
        unsigned int* c = cnt + (size_t)(bid & (NREP - 1)) * Ns;
        const int E4 = E >> 2;
        const int4* s4 = (const int4*)edge;   // edge base is 16B aligned
        for (int i = g; i < E4; i += NTH) {
            int4 e4 = s4[i];
            atomicAdd(&c[e4.x], 1u); atomicAdd(&c[e4.y], 1u);
            atomicAdd(&c[e4.z], 1u); atomicAdd(&c[e4.w], 1u);
        }
        if (g < (E & 3)) atomicAdd(&cnt[edge[(E4 << 2) + g]], 1u);
    }
    grid.sync();

    // ---------------- P2: weighted column sum of x_src -> pT[h][b] ----------------
    // Block b, wave rowOff handles rows n = b*4+rowOff + k*(GB*4); 64 lanes x float4 = 1KB/row.
    // 4 independent accumulators (acc[k&3] with full unroll -> static index) for MLP.
    {
        const int rowOff = tid >> 6;
        const int colgrp = tid & 63;
        const int base = bid * 4 + rowOff;
        float4 acc[4];
        acc[0] = acc[1] = acc[2] = acc[3] = make_float4(0.f, 0.f, 0.f, 0.f);
        // 17*GB*4 = 52224 >= Ns=50000 rows covered by the unrolled slots.
        #pragma unroll
        for (int k = 0; k < 17; ++k) {
            int n = base + k * (GB * 4);
            if (n < Ns) {
                float c = 0.f;
                #pragma unroll
                for (int r = 0; r < NREP; ++r) c += (float)cnt[(size_t)r * Ns + n];
                float4 x = xs4[(size_t)n * 64 + colgrp];
                acc[k & 3].x += c * x.x; acc[k & 3].y += c * x.y;
                acc[k & 3].z += c * x.z; acc[k & 3].w += c * x.w;
            }
        }
        // defensive tail for Ns > 52224 (not hit at Ns=50000)
        for (int n = base + 17 * (GB * 4); n < Ns; n += GB * 4) {
            float c = 0.f;
            #pragma unroll
            for (int r = 0; r < NREP; ++r) c += (float)cnt[(size_t)r * Ns + n];
            float4 x = xs4[(size_t)n * 64 + colgrp];
            acc[0].x += c * x.x; acc[0].y += c * x.y;
            acc[0].z += c * x.z; acc[0].w += c * x.w;
        }
        float4 a;
        a.x = (acc[0].x + acc[1].x) + (acc[2].x + acc[3].x);
        a.y = (acc[0].y + acc[1].y) + (acc[2].y + acc[3].y);
        a.z = (acc[0].z + acc[1].z) + (acc[2].z + acc[3].z);
        a.w = (acc[0].w + acc[1].w) + (acc[2].w + acc[3].w);
        const int col = colgrp * 4;
        sred[rowOff * HDIM + col + 0] = a.x;
        sred[rowOff * HDIM + col + 1] = a.y;
        sred[rowOff * HDIM + col + 2] = a.z;
        sred[rowOff * HDIM + col + 3] = a.w;
        __syncthreads();
        float part = (sred[tid] + sred[HDIM + tid]) + (sred[2 * HDIM + tid] + sred[3 * HDIM + tid]);
        pT[(size_t)tid * GB + bid] = part;   // transposed store -> coalesced reduce in P3
        __syncthreads();                     // sred reused next phase
    }
    grid.sync();

    // ---------------- P3: ls[h] = sum_b pT[h][b]  (blocks 0..255, coalesced) -------
    if (bid < HDIM) {
        const float* row = pT + (size_t)bid * GB;
        float a = 0.f;
        #pragma unroll
        for (int j = 0; j < GB / BT; ++j) a += row[tid + j * BT];
        #pragma unroll
        for (int o = 32; o > 0; o >>= 1) a += __shfl_down(a, o, 64);
        if ((tid & 63) == 0) sred[tid >> 6] = a;
        __syncthreads();
        if (tid == 0) ls[bid] = (sred[0] + sred[1]) + (sred[2] + sred[3]);
        __syncthreads();
    }
    grid.sync();

    // ---------------- P4: vv[j] = R[j,:] . ls  (blocks 0..255) --------------------
    if (bid < HDIM) {
        float a = Rm[(size_t)bid * HDIM + tid] * ls[tid];
        #pragma unroll
        for (int o = 32; o > 0; o >>= 1) a += __shfl_down(a, o, 64);
        if ((tid & 63) == 0) sred[tid >> 6] = a;
        __syncthreads();
        if (tid == 0) vv[bid] = (sred[0] + sred[1]) + (sred[2] + sred[3]);
        __syncthreads();
    }
    grid.sync();

    // ---------------- P5: t[n] = x_trg[n] . vv  (wave per row, unroll-2) ----------
    {
        const int lane = tid & 63;
        const float4 vr = ((const float4*)vv)[lane];
        const int nw = NTH >> 6;        // total waves = 3072
        int n = g >> 6;                 // this wave's first row
        for (; n + nw < Nt; n += 2 * nw) {
            float4 xa = xt4[(size_t)n * 64 + lane];
            float4 xb = xt4[(size_t)(n + nw) * 64 + lane];
            float da = xa.x * vr.x + xa.y * vr.y + xa.z * vr.z + xa.w * vr.w;
            float db = xb.x * vr.x + xb.y * vr.y + xb.z * vr.z + xb.w * vr.w;
            #pragma unroll
            for (int o = 32; o > 0; o >>= 1) {
                da += __shfl_down(da, o, 64);
                db += __shfl_down(db, o, 64);
            }
            if (lane == 0) { t[n] = da; t[n + nw] = db; }
        }
        if (n < Nt) {
            float4 xa = xt4[(size_t)n * 64 + lane];
            float da = xa.x * vr.x + xa.y * vr.y + xa.z * vr.z + xa.w * vr.w;
            #pragma unroll
            for (int o = 32; o > 0; o >>= 1) da += __shfl_down(da, o, 64);
            if (lane == 0) t[n] = da;
        }
    }
    grid.sync();

    // ---------------- P6: out[e] = t[trg[e]] (vectorized gather) ------------------
    {
        const int* trg = edge + E;
        if ((E & 3) == 0) {
            const int4* trg4 = (const int4*)trg;   // aligned since E%4==0
            float4* out4 = (float4*)out;
            const int E4 = E >> 2;
            for (int i = g; i < E4; i += NTH) {
                int4 e4 = trg4[i];
                out4[i] = make_float4(t[e4.x], t[e4.y], t[e4.z], t[e4.w]);
            }
        } else {
            for (int e = g; e < E; e += NTH) out[e] = t[trg[e]];
        }
    }
}

extern "C" void kernel_launch(void* const* d_in, const int* in_sizes, int n_in,
                              void* d_out, int out_size, void* d_ws, size_t ws_size,
                              hipStream_t stream) {
    const float4* xs4 = (const float4*)d_in[0];
    const float4* xt4 = (const float4*)d_in[1];
    const float*  Rm  = (const float*)d_in[2];
    const int*    edge = (const int*)d_in[3];
    float* out = (float*)d_out;

    int Ns = in_sizes[0] / HDIM;
    int Nt = in_sizes[1] / HDIM;
    int E  = in_sizes[3] / 2;

    // Workspace carve-out (256B-aligned slices).
    char* ws = (char*)d_ws;
    size_t off = 0;
    auto alloc = [&](size_t bytes) -> void* {
        void* p = ws + off;
        off = (off + bytes + 255) & ~(size_t)255;
        return p;
    };
    unsigned int* cnt = (unsigned int*)alloc((size_t)NREP * Ns * sizeof(unsigned int)); // 1.6MB
    float* pT = (float*)alloc((size_t)HDIM * GB * sizeof(float));                       // 768KB
    float* ls = (float*)alloc(HDIM * sizeof(float));
    float* vv = (float*)alloc(HDIM * sizeof(float));
    float* t  = (float*)alloc((size_t)Nt * sizeof(float));
    (void)ws_size; (void)n_in; (void)out_size;

    void* args[13] = {
        (void*)&xs4, (void*)&xt4, (void*)&Rm, (void*)&edge,
        (void*)&Ns, (void*)&Nt, (void*)&E,
        (void*)&cnt, (void*)&pT, (void*)&ls, (void*)&vv, (void*)&t, (void*)&out
    };
    hipLaunchCooperativeKernel((void*)k_fused, dim3(GB), dim3(BT), args, 0, stream);
}

// Round 8
// 61.417 us; speedup vs baseline: 8.8548x; 8.8548x over previous
//
#include <hip/hip_runtime.h>

#define HDIM 256
#define CSB  512             // colsum blocks; partials pT is [HDIM][CSB]
#define RSTRIDE (CSB * 4)    // row stride per colsum block-iteration

// ---------------- Stage 0: zero the histogram ----------------
__global__ void k_zero(uint4* __restrict__ p, int n4) {
    int i = blockIdx.x * blockDim.x + threadIdx.x;
    if (i < n4) p[i] = make_uint4(0u, 0u, 0u, 0u);
}

// ---------------- Stage 1: histogram of src indices ----------------
// 300K atomics over 50K addresses (~24/line): spread-address, no fences -> fast.
__global__ void k_count(const int4* __restrict__ src4, const int* __restrict__ src,
                        int E, unsigned int* __restrict__ cnt) {
    int i = blockIdx.x * blockDim.x + threadIdx.x;
    int E4 = E >> 2;
    if (i < E4) {
        int4 v = src4[i];
        atomicAdd(&cnt[v.x], 1u); atomicAdd(&cnt[v.y], 1u);
        atomicAdd(&cnt[v.z], 1u); atomicAdd(&cnt[v.w], 1u);
    }
    if (i < (E & 3)) atomicAdd(&cnt[src[(E4 << 2) + i]], 1u);
}

// ---------------- Stage 2: weighted column sum -> transposed partials ----------------
// 512 blocks x 256 thr (4 waves). Wave handles rows n = bid*4+rowOff + k*RSTRIDE.
// 8 independent guarded row-bodies per outer iteration => ~8.5KB in flight per wave.
__global__ __launch_bounds__(256)
void k_colsum(const float4* __restrict__ xs4,
              const unsigned int* __restrict__ cnt,
              int Ns, float* __restrict__ pT) {
    const int colgrp = threadIdx.x & 63;
    const int rowOff = threadIdx.x >> 6;
    const int bid = blockIdx.x;
    float4 acc = make_float4(0.f, 0.f, 0.f, 0.f);

    for (int n = bid * 4 + rowOff; n < Ns; n += 8 * RSTRIDE) {
        float  c[8];
        float4 x[8];
        #pragma unroll
        for (int j = 0; j < 8; ++j) {           // issue all loads first (wave-uniform guards)
            int r = n + j * RSTRIDE;
            c[j] = 0.f;
            x[j] = make_float4(0.f, 0.f, 0.f, 0.f);
            if (r < Ns) {
                c[j] = (float)cnt[r];
                x[j] = xs4[(size_t)r * 64 + colgrp];
            }
        }
        #pragma unroll
        for (int j = 0; j < 8; ++j) {
            acc.x += c[j] * x[j].x; acc.y += c[j] * x[j].y;
            acc.z += c[j] * x[j].z; acc.w += c[j] * x[j].w;
        }
    }

    __shared__ float s[4 * HDIM];
    const int col = colgrp * 4;
    s[rowOff * HDIM + col + 0] = acc.x;
    s[rowOff * HDIM + col + 1] = acc.y;
    s[rowOff * HDIM + col + 2] = acc.z;
    s[rowOff * HDIM + col + 3] = acc.w;
    __syncthreads();
    const int tid = threadIdx.x;
    float part = (s[tid] + s[HDIM + tid]) + (s[2 * HDIM + tid] + s[3 * HDIM + tid]);
    pT[(size_t)tid * CSB + bid] = part;         // transposed -> coalesced reduce
}

// ---------------- Stage 3: ls[h] = sum_b pT[h][b] ----------------
// 256 blocks; block h reads its contiguous 2KB row. ~1us chip-wide.
__global__ __launch_bounds__(256)
void k_reduceT(const float* __restrict__ pT, float* __restrict__ ls) {
    const int h = blockIdx.x;
    const int tid = threadIdx.x;
    const float* row = pT + (size_t)h * CSB;
    float a = row[tid] + row[tid + 256];
    #pragma unroll
    for (int o = 32; o > 0; o >>= 1) a += __shfl_down(a, o, 64);
    __shared__ float s[4];
    if ((tid & 63) == 0) s[tid >> 6] = a;
    __syncthreads();
    if (tid == 0) ls[h] = (s[0] + s[1]) + (s[2] + s[3]);
}

// ---------------- Stage 4: v = R @ ls (one block, row per thread) ----------------
__global__ __launch_bounds__(256)
void k_matvec(const float* __restrict__ Rm, const float* __restrict__ ls,
              float* __restrict__ v) {
    __shared__ float lss[HDIM];
    const int i = threadIdx.x;
    lss[i] = ls[i];
    __syncthreads();
    const float4* R4 = (const float4*)(Rm + (size_t)i * HDIM);
    float acc = 0.f;
    #pragma unroll
    for (int j = 0; j < 64; ++j) {
        float4 r = R4[j];
        acc += r.x * lss[4 * j] + r.y * lss[4 * j + 1] + r.z * lss[4 * j + 2] + r.w * lss[4 * j + 3];
    }
    v[i] = acc;
}

// ---------------- Stage 5: t[n] = x_trg[n] . v (wave/row, unroll-4) ----------------
__global__ __launch_bounds__(256)
void k_rowdot(const float4* __restrict__ xt4, const float* __restrict__ v,
              int N, float* __restrict__ t) {
    const int lane = threadIdx.x & 63;
    const float4 vr = ((const float4*)v)[lane];
    const int nw = (gridDim.x * blockDim.x) >> 6;   // total waves
    const int n0 = (blockIdx.x * blockDim.x + threadIdx.x) >> 6;

    for (int n = n0; n < N; n += 4 * nw) {
        float d[4] = {0.f, 0.f, 0.f, 0.f};
        #pragma unroll
        for (int j = 0; j < 4; ++j) {              // 4 independent rows in flight
            int r = n + j * nw;
            if (r < N) {
                float4 x = xt4[(size_t)r * 64 + lane];
                d[j] = x.x * vr.x + x.y * vr.y + x.z * vr.z + x.w * vr.w;
            }
        }
        #pragma unroll
        for (int o = 32; o > 0; o >>= 1) {
            #pragma unroll
            for (int j = 0; j < 4; ++j) d[j] += __shfl_down(d[j], o, 64);
        }
        if (lane == 0) {
            #pragma unroll
            for (int j = 0; j < 4; ++j) {
                int r = n + j * nw;
                if (r < N) t[r] = d[j];
            }
        }
    }
}

// ---------------- Stage 6: out[e] = t[trg[e]] (vectorized gather) ----------------
__global__ void k_gather(const int4* __restrict__ trg4, const int* __restrict__ trg, int E,
                         const float* __restrict__ t,
                         float4* __restrict__ out4, float* __restrict__ out) {
    int i = blockIdx.x * blockDim.x + threadIdx.x;
    int E4 = E >> 2;
    if (i < E4) {
        int4 v = trg4[i];
        out4[i] = make_float4(t[v.x], t[v.y], t[v.z], t[v.w]);
    }
    if (i < (E & 3)) {
        int e = (E4 << 2) + i;
        out[e] = t[trg[e]];
    }
}

extern "C" void kernel_launch(void* const* d_in, const int* in_sizes, int n_in,
                              void* d_out, int out_size, void* d_ws, size_t ws_size,
                              hipStream_t stream) {
    const float* x_src = (const float*)d_in[0];
    const float* x_trg = (const float*)d_in[1];
    const float* Rm    = (const float*)d_in[2];
    const int*   edge  = (const int*)d_in[3];   // [0..E)=src, [E..2E)=trg
    float* out = (float*)d_out;

    const int Ns = in_sizes[0] / HDIM;
    const int Nt = in_sizes[1] / HDIM;
    const int E  = in_sizes[3] / 2;

    // Workspace carve-out (256B-aligned slices).
    char* ws = (char*)d_ws;
    size_t off = 0;
    auto alloc = [&](size_t bytes) -> void* {
        void* p = ws + off;
        off = (off + bytes + 255) & ~(size_t)255;
        return p;
    };
    unsigned int* cnt = (unsigned int*)alloc((size_t)Ns * sizeof(unsigned int)); // 200KB
    float* pT = (float*)alloc((size_t)HDIM * CSB * sizeof(float));               // 512KB
    float* ls = (float*)alloc(HDIM * sizeof(float));
    float* v  = (float*)alloc(HDIM * sizeof(float));
    float* t  = (float*)alloc((size_t)Nt * sizeof(float));
    (void)ws_size; (void)n_in; (void)out_size;

    const int n4 = (Ns + 3) / 4;
    k_zero<<<(n4 + 255) / 256, 256, 0, stream>>>((uint4*)cnt, n4);

    const int E4 = E >> 2;
    const int cntThreads = (E4 > 0 ? E4 : 1);
    k_count<<<(cntThreads + 255) / 256, 256, 0, stream>>>(
        (const int4*)edge, edge, E, cnt);

    k_colsum<<<CSB, 256, 0, stream>>>((const float4*)x_src, cnt, Ns, pT);

    k_reduceT<<<HDIM, 256, 0, stream>>>(pT, ls);

    k_matvec<<<1, 256, 0, stream>>>(Rm, ls, v);

    k_rowdot<<<1024, 256, 0, stream>>>((const float4*)x_trg, v, Nt, t);

    k_gather<<<(cntThreads + 255) / 256, 256, 0, stream>>>(
        (const int4*)(edge + E), edge + E, E, t, (float4*)out, out);
}